// Round 12
// baseline (203.742 us; speedup 1.0000x reference)
//
#include <hip/hip_runtime.h>

#define DIM   128
#define CPT   256         // chars per wave-chunk
#define TAIL  64          // staged lookahead for cross-chunk tails
#define WPB   4           // waves per block

typedef float vf2 __attribute__((ext_vector_type(2)));
typedef float vf4 __attribute__((ext_vector_type(4)));

// out = N - <H,T>_F / (||H||_F ||T||_F).  T never materialized.
// Lane = 2 columns (vf2): one global_load_dwordx2 per wave = 512 B = one
// FULL char row (vs 2 slice passes in R7 -> half the loads, half the waves,
// staging/masks computed once). Control is wave-uniform: segment boundaries
// live in SGPR ballot masks, tested on the scalar pipe. Ent loads (flush hv,
// hh stream) are nontemporal so the 5.12 MB char table stays L2-resident.
__global__ __launch_bounds__(256) void fused_kernel(
    const float* __restrict__ char_emb,
    const float* __restrict__ ent,
    const int* __restrict__ head_ids,
    const int* __restrict__ char_ids,
    const int* __restrict__ seg_ids,
    float* __restrict__ pb,        // [gridDim.x*3] block partials: ht,tt,hh
    int total_chars, int n_triples, int hh_per_block)
{
    __shared__ __align__(16) int s_off[WPB][CPT + TAIL];  // cid<<9 (row byte off)
    __shared__ int s_sid[WPB][CPT + TAIL];
    __shared__ float r_scr[3][WPB];

    const int tid  = threadIdx.x;
    const int lane = tid & 63;
    const int wid  = tid >> 6;
    const int colb = lane << 3;               // byte offset of lane's 2 columns

    float ht = 0.f, tt = 0.f, hh = 0.f;

    const int chunk = blockIdx.x * WPB + wid;
    const int start = chunk * CPT;
    const int len   = min(CPT, total_chars - start);
    const int sl    = min(CPT + TAIL, total_chars - start);
    const char* cb  = (const char*)char_emb + colb;
    const char* eb  = (const char*)ent + colb;

    // ---- stage offsets + sids (wave-local region) ----
    for (int c = lane; c < sl; c += 64) {
        s_off[wid][c] = char_ids[start + c] << 9;
        s_sid[wid][c] = seg_ids[start + c];
    }
    // ---- boundary masks, kept in SGPRs (ballot is wave-uniform) ----
    unsigned long long mk[4] = {0ull, 0ull, 0ull, 0ull};
    if (len == CPT) {
#pragma unroll
        for (int grp = 0; grp < 4; ++grp) {
            const int c = start + grp * 64 + lane;
            const int s1 = seg_ids[c];
            const int s0 = (c > 0) ? seg_ids[c - 1] : (s1 + 1); // char 0: boundary
            mk[grp] = __ballot(s1 != s0);
        }
    }
    __syncthreads();

    if (len == CPT) {
        // -------- fast path --------
        int cur = __builtin_amdgcn_readfirstlane(s_sid[wid][0]);
        vf2 hv = __builtin_nontemporal_load(
            (const vf2*)(eb + ((size_t)(unsigned)head_ids[cur] << 9)));
        vf2 acc = (vf2){0.f, 0.f};
        bool live = false;      // first flush dropped iff chunk starts mid-segment
        vf2 vA[16], vB[16];

#define PF(BUF, B) { \
    _Pragma("unroll") \
    for (int q = 0; q < 4; ++q) { \
        const int4 o4 = *(const int4*)&s_off[wid][(B) * 16 + q * 4]; \
        BUF[q * 4 + 0] = *(const vf2*)(cb + (size_t)(unsigned)o4.x); \
        BUF[q * 4 + 1] = *(const vf2*)(cb + (size_t)(unsigned)o4.y); \
        BUF[q * 4 + 2] = *(const vf2*)(cb + (size_t)(unsigned)o4.z); \
        BUF[q * 4 + 3] = *(const vf2*)(cb + (size_t)(unsigned)o4.w); \
    } }

#define CS(BUF, B) { \
    _Pragma("unroll") \
    for (int j = 0; j < 16; ++j) { \
        if (mk[(B) >> 2] & (1ull << (((B) & 3) * 16 + j))) {   /* scalar test */ \
            if (live) { \
                ht = fmaf(hv.x, acc.x, ht); ht = fmaf(hv.y, acc.y, ht); \
                tt = fmaf(acc.x, acc.x, tt); tt = fmaf(acc.y, acc.y, tt); \
            } \
            live = true; \
            acc = (vf2){0.f, 0.f}; \
            cur = __builtin_amdgcn_readfirstlane(s_sid[wid][(B) * 16 + j]); \
            hv = __builtin_nontemporal_load( \
                (const vf2*)(eb + ((size_t)(unsigned)head_ids[cur] << 9))); \
        } \
        acc.x += BUF[j].x; acc.y += BUF[j].y; \
    } }

        PF(vA, 0)
#pragma unroll
        for (int B = 0; B < 16; ++B) {
            if (B + 1 < 16) { if (B & 1) { PF(vA, B + 1) } else { PF(vB, B + 1) } }
            if (B & 1) { CS(vB, B) } else { CS(vA, B) }
        }
#undef PF
#undef CS

        if (live) {
            // tail: last owned segment may continue past chunk end
            int e = CPT;
            bool ended = false;
            while (e < sl) {
                const int idx = e + lane;
                const bool differ = (idx < sl) && (s_sid[wid][idx] != cur);
                const unsigned long long bm = __ballot(differ);
                const int run = bm ? (__ffsll((long long)bm) - 1)
                                   : min(64, sl - e);
                for (int j = 0; j < run; j += 4) {
                    const int mm2 = min(4, run - j);
                    vf2 vv[4];
#pragma unroll
                    for (int k = 0; k < 4; ++k) {
                        if (k < mm2)
                            vv[k] = *(const vf2*)(cb +
                                (size_t)(unsigned)s_off[wid][e + j + k]);
                    }
                    for (int k = 0; k < mm2; ++k) {
                        acc.x += vv[k].x; acc.y += vv[k].y;
                    }
                }
                e += run;
                if (bm) { ended = true; break; }
            }
            if (!ended && start + sl < total_chars) {
                int gg = start + sl;                 // very rare long run
                while (gg < total_chars && seg_ids[gg] == cur) {
                    const vf2 v = *(const vf2*)(cb +
                        (size_t)(unsigned)(char_ids[gg] << 9));
                    acc.x += v.x; acc.y += v.y;
                    ++gg;
                }
            }
            // final flush
            ht = fmaf(hv.x, acc.x, ht); ht = fmaf(hv.y, acc.y, ht);
            tt = fmaf(acc.x, acc.x, tt); tt = fmaf(acc.y, acc.y, tt);
        }
    } else if (len > 0) {
        // -------- rare fallback (partial last chunk): scalar per char --------
        int p = 0;
        if (start > 0) {
            const int prev = seg_ids[start - 1];
            while (p < len && seg_ids[start + p] == prev) ++p;
        }
        if (p < len) {
            int cur = seg_ids[start + p];
            vf2 acc = (vf2){0.f, 0.f};
            vf2 hv = __builtin_nontemporal_load(
                (const vf2*)(eb + ((size_t)(unsigned)head_ids[cur] << 9)));
            for (int c = p; c < len; ++c) {
                const int sid = seg_ids[start + c];
                if (sid != cur) {
                    ht += hv.x * acc.x + hv.y * acc.y;
                    tt += acc.x * acc.x + acc.y * acc.y;
                    acc = (vf2){0.f, 0.f}; cur = sid;
                    hv = __builtin_nontemporal_load(
                        (const vf2*)(eb + ((size_t)(unsigned)head_ids[cur] << 9)));
                }
                const vf2 v = *(const vf2*)(cb +
                    (size_t)(unsigned)(char_ids[start + c] << 9));
                acc.x += v.x; acc.y += v.y;
            }
            int gg = start + len;
            while (gg < total_chars && seg_ids[gg] == cur) {
                const vf2 v = *(const vf2*)(cb +
                    (size_t)(unsigned)(char_ids[gg] << 9));
                acc.x += v.x; acc.y += v.y;
                ++gg;
            }
            ht += hv.x * acc.x + hv.y * acc.y;
            tt += acc.x * acc.x + acc.y * acc.y;
        }
    }

    // -------- hh strip for this block (covers empty segments exactly) --------
    {
        const vf4* e4 = (const vf4*)ent;
        const long base = (long)blockIdx.x * hh_per_block * 32;
        const long lim  = (long)n_triples * 32;
        for (int s = tid; s < hh_per_block * 32; s += 256) {
            const long f2 = base + s;
            if (f2 < lim) {
                const int row = (int)(f2 >> 5);
                const int hid = head_ids[row];
                const vf4 v = __builtin_nontemporal_load(
                    e4 + (size_t)hid * 32 + (int)(f2 & 31));
                hh += v.x * v.x + v.y * v.y + v.z * v.z + v.w * v.w;
            }
        }
    }

    // -------- block reduce -> per-block partials (no atomics, no memset) ----
#pragma unroll
    for (int off = 32; off > 0; off >>= 1) {
        ht += __shfl_down(ht, off);
        tt += __shfl_down(tt, off);
        hh += __shfl_down(hh, off);
    }
    if (lane == 0) { r_scr[0][wid] = ht; r_scr[1][wid] = tt; r_scr[2][wid] = hh; }
    __syncthreads();
    if (tid == 0) {
        float a = 0.f, b = 0.f, c = 0.f;
#pragma unroll
        for (int w = 0; w < WPB; ++w) {
            a += r_scr[0][w]; b += r_scr[1][w]; c += r_scr[2][w];
        }
        pb[blockIdx.x * 3 + 0] = a;
        pb[blockIdx.x * 3 + 1] = b;
        pb[blockIdx.x * 3 + 2] = c;
    }
}

// final reduce: sums partials in double, writes N - ht/sqrt(hh*tt)
__global__ __launch_bounds__(256) void reduce_kernel(
    const float* __restrict__ pb, int nb, float* __restrict__ out,
    int n_triples)
{
    double ht = 0.0, tt = 0.0, hh = 0.0;
    for (int i = threadIdx.x; i < nb; i += 256) {
        ht += (double)pb[i * 3 + 0];
        tt += (double)pb[i * 3 + 1];
        hh += (double)pb[i * 3 + 2];
    }
#pragma unroll
    for (int off = 32; off > 0; off >>= 1) {
        ht += __shfl_down(ht, off);
        tt += __shfl_down(tt, off);
        hh += __shfl_down(hh, off);
    }
    __shared__ double sd[3][4];
    const int wid = threadIdx.x >> 6;
    if ((threadIdx.x & 63) == 0) { sd[0][wid] = ht; sd[1][wid] = tt; sd[2][wid] = hh; }
    __syncthreads();
    if (threadIdx.x == 0) {
        double a = 0.0, b = 0.0, c = 0.0;
        for (int w = 0; w < 4; ++w) { a += sd[0][w]; b += sd[1][w]; c += sd[2][w]; }
        out[0] = (float)((double)n_triples - a / sqrt(c * b));
    }
}

extern "C" void kernel_launch(void* const* d_in, const int* in_sizes, int n_in,
                              void* d_out, int out_size, void* d_ws, size_t ws_size,
                              hipStream_t stream)
{
    const float* char_emb = (const float*)d_in[0];
    const float* ent_emb  = (const float*)d_in[1];
    const int* head_ids   = (const int*)d_in[2];
    const int* char_ids   = (const int*)d_in[3];
    const int* seg_ids    = (const int*)d_in[4];
    const int n_triples   = in_sizes[2];
    const int total_chars = in_sizes[3];

    const int n_chunks = (total_chars + CPT - 1) / CPT;
    const int nsb = (n_chunks + WPB - 1) / WPB;    // single pass, no slices
    const int hhpb = (n_triples + nsb - 1) / nsb;

    float* pb = (float*)d_ws;                      // nsb*3 floats

    fused_kernel<<<nsb, 256, 0, stream>>>(char_emb, ent_emb, head_ids,
                                          char_ids, seg_ids, pb,
                                          total_chars, n_triples, hhpb);
    reduce_kernel<<<1, 256, 0, stream>>>(pb, nsb, (float*)d_out, n_triples);
}